// Round 4
// baseline (957.902 us; speedup 1.0000x reference)
//
#include <hip/hip_runtime.h>
#include <hip/hip_bf16.h>
#include <cstddef>

// Problem constants (fixed by setup_inputs)
#define TOTAL   1536
#define HIDDEN  1024
#define HK      8
#define HV      16
#define DK      64
#define DV      64
#define KSZ     4
#define KEY_DIM 512
#define VAL_DIM 1024
#define CONV_DIM 2048
#define NSEQ    4

typedef unsigned short bfu;  // bf16 bits

__device__ __forceinline__ float b2f(bfu u) {
    return __uint_as_float(((unsigned)u) << 16);
}
__device__ __forceinline__ bfu f2b(float f) {  // round-to-nearest-even (finite)
    unsigned x = __float_as_uint(f);
    return (bfu)((x + 0x7FFFu + ((x >> 16) & 1u)) >> 16);
}

__device__ __forceinline__ float4 load4(const float* p) { return *(const float4*)p; }
__device__ __forceinline__ float4 load4(const bfu* p) {
    ushort4 u = *(const ushort4*)p;  // 8B aligned at all call sites
    float4 r;
    r.x = b2f(u.x); r.y = b2f(u.y); r.z = b2f(u.z); r.w = b2f(u.w);
    return r;
}
__device__ __forceinline__ void store4(float* p, float a, float b, float c, float d) {
    float4 v = {a, b, c, d};
    *(float4*)p = v;
}
__device__ __forceinline__ void store4(bfu* p, float a, float b, float c, float d) {
    ushort4 o;
    o.x = f2b(a); o.y = f2b(b); o.z = f2b(c); o.w = f2b(d);
    *(ushort4*)p = o;
}

// ---------------------------------------------------------------------------
// GEMM: C[M,N] = A[M,K] @ B[N,K]^T.  A fp32 or bf16; B fp32; C fp32 or bf16.
// 64x64 tile, BK=16, 256 threads, 4x4 microtile.
// ---------------------------------------------------------------------------
template <typename TA, typename TC>
__global__ __launch_bounds__(256) void gemm_tn(const TA* __restrict__ A,
                                               const float* __restrict__ B,
                                               TC* __restrict__ C,
                                               int M, int N, int K) {
    __shared__ float As[16][68];
    __shared__ float Bs[16][68];
    const int tid = threadIdx.x;
    const int m0 = blockIdx.y * 64;
    const int n0 = blockIdx.x * 64;
    const int lr = tid >> 2;           // 0..63 row within tile
    const int lk = (tid & 3) << 2;     // 0,4,8,12 k offset
    const int tm = tid >> 4;           // 0..15
    const int tn = tid & 15;           // 0..15
    float acc[4][4] = {};

    const TA* Ap = A + (size_t)(m0 + lr) * K + lk;
    const float* Bp = B + (size_t)(n0 + lr) * K + lk;

    for (int kk = 0; kk < K; kk += 16) {
        float4 av = load4(Ap + kk);
        float4 bv = load4(Bp + kk);
        As[lk + 0][lr] = av.x; As[lk + 1][lr] = av.y;
        As[lk + 2][lr] = av.z; As[lk + 3][lr] = av.w;
        Bs[lk + 0][lr] = bv.x; Bs[lk + 1][lr] = bv.y;
        Bs[lk + 2][lr] = bv.z; Bs[lk + 3][lr] = bv.w;
        __syncthreads();
#pragma unroll
        for (int k2 = 0; k2 < 16; ++k2) {
            float4 a4 = *(const float4*)&As[k2][tm * 4];
            float4 b4 = *(const float4*)&Bs[k2][tn * 4];
            float ar[4] = {a4.x, a4.y, a4.z, a4.w};
            float br[4] = {b4.x, b4.y, b4.z, b4.w};
#pragma unroll
            for (int i = 0; i < 4; ++i)
#pragma unroll
                for (int j = 0; j < 4; ++j) acc[i][j] += ar[i] * br[j];
        }
        __syncthreads();
    }

#pragma unroll
    for (int i = 0; i < 4; ++i) {
        int m = m0 + tm * 4 + i;
        int n = n0 + tn * 4;
        store4(&C[(size_t)m * N + n], acc[i][0], acc[i][1], acc[i][2], acc[i][3]);
    }
}

// ---------------------------------------------------------------------------
// b/a projections + beta = sigmoid(b), gamma = exp(-exp(A_log)*softplus(a+dtb))
// One lane per output, full K=1024 dot per lane.
// ---------------------------------------------------------------------------
__global__ __launch_bounds__(64) void proj_ba(const float* __restrict__ H,
                                              const float* __restrict__ Wb,
                                              const float* __restrict__ Wa,
                                              const float* __restrict__ dtb,
                                              const float* __restrict__ Alog,
                                              float* __restrict__ betab,
                                              float* __restrict__ gammab) {
    const int tok = blockIdx.x;
    const int lane = threadIdx.x;
    if (lane >= 32) return;
    const float* w = (lane < 16) ? (Wb + (size_t)lane * HIDDEN)
                                 : (Wa + (size_t)(lane - 16) * HIDDEN);
    const float4* wp = (const float4*)w;
    const float4* hp = (const float4*)(H + (size_t)tok * HIDDEN);
    float s = 0.f;
    for (int i = 0; i < HIDDEN / 4; ++i) {
        float4 a = hp[i], c = wp[i];
        s += a.x * c.x + a.y * c.y + a.z * c.z + a.w * c.w;
    }
    if (lane < 16) {
        betab[tok * HV + lane] = 1.f / (1.f + expf(-s));
    } else {
        int hh = lane - 16;
        float x = s + dtb[hh];
        float sp = (x > 20.f) ? x : log1pf(expf(x));
        gammab[tok * HV + hh] = expf(-expf(Alog[hh]) * sp);
    }
}

// ---------------------------------------------------------------------------
// Causal depthwise conv(K=4) + silu, per-head L2 norm of q,k. Block per token.
// ---------------------------------------------------------------------------
__global__ __launch_bounds__(256) void conv_norm(const bfu* __restrict__ mixed,
                                                 const float* __restrict__ cw,
                                                 const int* __restrict__ cu,
                                                 bfu* __restrict__ qb,
                                                 bfu* __restrict__ kb,
                                                 bfu* __restrict__ vb) {
    const int tok = blockIdx.x;
    const int tid = threadIdx.x;
    __shared__ float yl[CONV_DIM];
    __shared__ float scale[16];

    int b = 0;
    for (int i = 1; i < NSEQ; ++i)
        if (tok >= cu[i]) b = i;
    const int pos = tok - cu[b];

    for (int c = tid; c < CONV_DIM; c += 256) {
        float acc = 0.f;
#pragma unroll
        for (int j = 0; j < KSZ; ++j) {
            int off = j - (KSZ - 1);
            float x = (pos + off >= 0) ? b2f(mixed[(size_t)(tok + off) * CONV_DIM + c]) : 0.f;
            acc += cw[c * KSZ + j] * x;
        }
        yl[c] = acc / (1.f + expf(-acc));  // silu
    }
    __syncthreads();

    if (tid < 16) {
        float p = 0.f;
        for (int u = 0; u < 64; ++u) {
            float v = yl[tid * 64 + u];
            p += v * v;
        }
        scale[tid] = rsqrtf(p + 1e-6f);
    }
    __syncthreads();

    for (int c = tid; c < CONV_DIM; c += 256) {
        float y = yl[c];
        if (c < KEY_DIM) {
            qb[(size_t)tok * KEY_DIM + c] = f2b(y * scale[c >> 6] * 0.125f);
        } else if (c < 2 * KEY_DIM) {
            kb[(size_t)tok * KEY_DIM + (c - KEY_DIM)] = f2b(y * scale[c >> 6]);
        } else {
            vb[(size_t)tok * VAL_DIM + (c - 2 * KEY_DIM)] = f2b(y);
        }
    }
}

// ---------------------------------------------------------------------------
// Gated delta rule recurrence. ONE WAVE per (seq, value-head).
// Thread dv owns state column S[0..63][dv] in fp32 registers.
// ---------------------------------------------------------------------------
__global__ __launch_bounds__(64) void delta_rec(const bfu* __restrict__ qb,
                                                const bfu* __restrict__ kb,
                                                const bfu* __restrict__ vb,
                                                const float* __restrict__ gammab,
                                                const float* __restrict__ betab,
                                                const int* __restrict__ cu,
                                                bfu* __restrict__ ob) {
    const int bh = blockIdx.x;
    const int b = bh >> 4, h = bh & 15, hk = h >> 1;
    const int dv = threadIdx.x;
    __shared__ float kl[64];
    __shared__ float ql[64];
    float S[64];
#pragma unroll
    for (int i = 0; i < 64; ++i) S[i] = 0.f;

    const int t0 = cu[b], t1 = cu[b + 1];
    for (int tok = t0; tok < t1; ++tok) {
        kl[dv] = b2f(kb[(size_t)tok * KEY_DIM + hk * 64 + dv]);
        ql[dv] = b2f(qb[(size_t)tok * KEY_DIM + hk * 64 + dv]);
        __syncthreads();
        const float gamma = gammab[tok * HV + h];
        const float bet = betab[tok * HV + h];
        const float vv = b2f(vb[(size_t)tok * VAL_DIM + h * 64 + dv]);

        float ks = 0.f;
#pragma unroll
        for (int i = 0; i < 64; ++i) {
            S[i] *= gamma;
            ks += kl[i] * S[i];
        }
        const float u = bet * (vv - ks);
        float o = 0.f;
#pragma unroll
        for (int i = 0; i < 64; ++i) {
            S[i] += kl[i] * u;
            o += ql[i] * S[i];
        }
        ob[(size_t)tok * VAL_DIM + h * 64 + dv] = f2b(o);
        __syncthreads();
    }
}

// ---------------------------------------------------------------------------
// Gated RMSNorm (in-place): o * rsqrt(mean(o^2)+eps) * nw * silu(z).
// ---------------------------------------------------------------------------
__global__ __launch_bounds__(256) void gated_norm(bfu* __restrict__ ob,
                                                  const bfu* __restrict__ zb,
                                                  const float* __restrict__ nw) {
    const int wid = blockIdx.x * 4 + (threadIdx.x >> 6);
    const int lane = threadIdx.x & 63;
    const int tok = wid >> 4, h = wid & 15;
    const size_t idx = (size_t)tok * VAL_DIM + h * 64 + lane;
    const float o = b2f(ob[idx]);
    float ss = o * o;
#pragma unroll
    for (int m = 1; m < 64; m <<= 1) ss += __shfl_xor(ss, m);
    const float r = rsqrtf(ss * (1.f / 64.f) + 1e-6f);
    const float z = b2f(zb[idx]);
    const float sz = z / (1.f + expf(-z));
    ob[idx] = f2b(o * r * nw[lane] * sz);
}

// ---------------------------------------------------------------------------
extern "C" void kernel_launch(void* const* d_in, const int* in_sizes, int n_in,
                              void* d_out, int out_size, void* d_ws, size_t ws_size,
                              hipStream_t stream) {
    const float* H    = (const float*)d_in[0];
    const float* Wqkv = (const float*)d_in[1];
    const float* Wz   = (const float*)d_in[2];
    const float* Wb   = (const float*)d_in[3];
    const float* Wa   = (const float*)d_in[4];
    const float* cwt  = (const float*)d_in[5];
    const float* dtb  = (const float*)d_in[6];
    const float* Alog = (const float*)d_in[7];
    const float* nw   = (const float*)d_in[8];
    const float* Wout = (const float*)d_in[9];
    const int*   cu   = (const int*)d_in[10];
    float* out = (float*)d_out;   // reference output dtype is FP32

    // --- Workspace layout (bf16 intermediates, fp32 gamma/beta), ~12.8 MB ---
    bfu* wsb = (bfu*)d_ws;
    bfu* mixed = wsb;                                // [0, 3.1M elts) gemm1->conv
    bfu* obuf  = wsb;                                // alias of dead mixed
    bfu* qbuf  = wsb + (size_t)TOTAL * CONV_DIM;
    bfu* kbuf  = qbuf + (size_t)TOTAL * KEY_DIM;
    bfu* vbuf  = kbuf + (size_t)TOTAL * KEY_DIM;
    bfu* zbuf  = qbuf;                               // alias of dead q+k
    float* gbuf = (float*)(vbuf + (size_t)TOTAL * VAL_DIM);
    float* bbuf = gbuf + (size_t)TOTAL * HV;

    // 1) mixed = H @ W_qkv^T   (1536 x 2048) -> bf16
    gemm_tn<float, bfu><<<dim3(CONV_DIM / 64, TOTAL / 64), 256, 0, stream>>>(
        H, Wqkv, mixed, TOTAL, CONV_DIM, HIDDEN);
    // 2) beta / gamma (fp32)
    proj_ba<<<TOTAL, 64, 0, stream>>>(H, Wb, Wa, dtb, Alog, bbuf, gbuf);
    // 3) conv + silu + l2 norm -> q,k,v (bf16)
    conv_norm<<<TOTAL, 256, 0, stream>>>(mixed, cwt, cu, qbuf, kbuf, vbuf);
    // 4) gated delta recurrence -> o (bf16, aliases dead mixed)
    delta_rec<<<NSEQ * HV, 64, 0, stream>>>(qbuf, kbuf, vbuf, gbuf, bbuf, cu, obuf);
    // 5) z = H @ W_z^T (bf16, aliases dead q+k)
    gemm_tn<float, bfu><<<dim3(VAL_DIM / 64, TOTAL / 64), 256, 0, stream>>>(
        H, Wz, zbuf, TOTAL, VAL_DIM, HIDDEN);
    // 6) gated RMSNorm in-place on o
    gated_norm<<<TOTAL * HV / 4, 256, 0, stream>>>(obuf, zbuf, nw);
    // 7) out = o @ W_out^T -> FP32 d_out
    gemm_tn<bfu, float><<<dim3(HIDDEN / 64, TOTAL / 64), 256, 0, stream>>>(
        obuf, Wout, out, TOTAL, HIDDEN, VAL_DIM);
}

// Round 5
// 772.668 us; speedup vs baseline: 1.2397x; 1.2397x over previous
//
#include <hip/hip_runtime.h>
#include <hip/hip_bf16.h>
#include <cstddef>

// Problem constants (fixed by setup_inputs)
#define TOTAL   1536
#define HIDDEN  1024
#define HK      8
#define HV      16
#define DK      64
#define DV      64
#define KSZ     4
#define KEY_DIM 512
#define VAL_DIM 1024
#define CONV_DIM 2048
#define NSEQ    4

// ---------------------------------------------------------------------------
// GEMM: C[M,N] = A[M,K] @ B[N,K]^T, fp32. 64x64 tile, BK=16, 256 thr, 4x4 micro.
// ---------------------------------------------------------------------------
__global__ __launch_bounds__(256) void gemm_tn(const float* __restrict__ A,
                                               const float* __restrict__ B,
                                               float* __restrict__ C,
                                               int M, int N, int K) {
    __shared__ float As[16][68];
    __shared__ float Bs[16][68];
    const int tid = threadIdx.x;
    const int m0 = blockIdx.y * 64;
    const int n0 = blockIdx.x * 64;
    const int lr = tid >> 2;           // 0..63 row within tile
    const int lk = (tid & 3) << 2;     // 0,4,8,12 k offset
    const int tm = tid >> 4;           // 0..15
    const int tn = tid & 15;           // 0..15
    float acc[4][4] = {};

    const float* Ap = A + (size_t)(m0 + lr) * K + lk;
    const float* Bp = B + (size_t)(n0 + lr) * K + lk;

    for (int kk = 0; kk < K; kk += 16) {
        float4 av = *(const float4*)(Ap + kk);
        float4 bv = *(const float4*)(Bp + kk);
        As[lk + 0][lr] = av.x; As[lk + 1][lr] = av.y;
        As[lk + 2][lr] = av.z; As[lk + 3][lr] = av.w;
        Bs[lk + 0][lr] = bv.x; Bs[lk + 1][lr] = bv.y;
        Bs[lk + 2][lr] = bv.z; Bs[lk + 3][lr] = bv.w;
        __syncthreads();
#pragma unroll
        for (int k2 = 0; k2 < 16; ++k2) {
            float4 a4 = *(const float4*)&As[k2][tm * 4];
            float4 b4 = *(const float4*)&Bs[k2][tn * 4];
            float ar[4] = {a4.x, a4.y, a4.z, a4.w};
            float br[4] = {b4.x, b4.y, b4.z, b4.w};
#pragma unroll
            for (int i = 0; i < 4; ++i)
#pragma unroll
                for (int j = 0; j < 4; ++j) acc[i][j] += ar[i] * br[j];
        }
        __syncthreads();
    }

#pragma unroll
    for (int i = 0; i < 4; ++i) {
        int m = m0 + tm * 4 + i;
        int n = n0 + tn * 4;
        float4 v = {acc[i][0], acc[i][1], acc[i][2], acc[i][3]};
        *(float4*)&C[(size_t)m * N + n] = v;
    }
}

// ---------------------------------------------------------------------------
// b/a projections + beta = sigmoid(b), gamma = exp(-exp(A_log)*softplus(a+dtb))
// ---------------------------------------------------------------------------
__global__ __launch_bounds__(64) void proj_ba(const float* __restrict__ H,
                                              const float* __restrict__ Wb,
                                              const float* __restrict__ Wa,
                                              const float* __restrict__ dtb,
                                              const float* __restrict__ Alog,
                                              float* __restrict__ betab,
                                              float* __restrict__ gammab) {
    const int tok = blockIdx.x;
    const int lane = threadIdx.x;
    if (lane >= 32) return;
    const float* w = (lane < 16) ? (Wb + (size_t)lane * HIDDEN)
                                 : (Wa + (size_t)(lane - 16) * HIDDEN);
    const float4* wp = (const float4*)w;
    const float4* hp = (const float4*)(H + (size_t)tok * HIDDEN);
    float s = 0.f;
    for (int i = 0; i < HIDDEN / 4; ++i) {
        float4 a = hp[i], c = wp[i];
        s += a.x * c.x + a.y * c.y + a.z * c.z + a.w * c.w;
    }
    if (lane < 16) {
        betab[tok * HV + lane] = 1.f / (1.f + expf(-s));
    } else {
        int hh = lane - 16;
        float x = s + dtb[hh];
        float sp = (x > 20.f) ? x : log1pf(expf(x));
        gammab[tok * HV + hh] = expf(-expf(Alog[hh]) * sp);
    }
}

// ---------------------------------------------------------------------------
// Causal depthwise conv(K=4) + silu, per-head L2 norm of q,k. Block per token.
// ---------------------------------------------------------------------------
__global__ __launch_bounds__(256) void conv_norm(const float* __restrict__ mixed,
                                                 const float* __restrict__ cw,
                                                 const int* __restrict__ cu,
                                                 float* __restrict__ qb,
                                                 float* __restrict__ kb,
                                                 float* __restrict__ vb) {
    const int tok = blockIdx.x;
    const int tid = threadIdx.x;
    __shared__ float yl[CONV_DIM];
    __shared__ float scale[16];

    int b = 0;
    for (int i = 1; i < NSEQ; ++i)
        if (tok >= cu[i]) b = i;
    const int pos = tok - cu[b];

    for (int c = tid; c < CONV_DIM; c += 256) {
        float acc = 0.f;
#pragma unroll
        for (int j = 0; j < KSZ; ++j) {
            int off = j - (KSZ - 1);
            float x = (pos + off >= 0) ? mixed[(size_t)(tok + off) * CONV_DIM + c] : 0.f;
            acc += cw[c * KSZ + j] * x;
        }
        yl[c] = acc / (1.f + expf(-acc));  // silu
    }
    __syncthreads();

    if (tid < 16) {
        float p = 0.f;
        for (int u = 0; u < 64; ++u) {
            float v = yl[tid * 64 + u];
            p += v * v;
        }
        scale[tid] = rsqrtf(p + 1e-6f);
    }
    __syncthreads();

    for (int c = tid; c < CONV_DIM; c += 256) {
        float y = yl[c];
        if (c < KEY_DIM) {
            qb[(size_t)tok * KEY_DIM + c] = y * scale[c >> 6] * 0.125f;  // * DK^-0.5
        } else if (c < 2 * KEY_DIM) {
            kb[(size_t)tok * KEY_DIM + (c - KEY_DIM)] = y * scale[c >> 6];
        } else {
            vb[(size_t)tok * VAL_DIM + (c - 2 * KEY_DIM)] = y;
        }
    }
}

// ---------------------------------------------------------------------------
// Gated delta rule recurrence. One block (4 waves) per (seq, value-head).
// Wave w owns state rows [w*16, w*16+16); lane owns column dv = lane.
// Identity used: o = q^T(γS) + (q·k)·u  — allows ONE reduction barrier/step.
// Per step: B1 (k/q staged, dbuf) + B2 (ks/qs/qk partials) = 2 barriers.
// ---------------------------------------------------------------------------
__global__ __launch_bounds__(256) void delta_rec(const float* __restrict__ qb,
                                                 const float* __restrict__ kb,
                                                 const float* __restrict__ vb,
                                                 const float* __restrict__ gammab,
                                                 const float* __restrict__ betab,
                                                 const int* __restrict__ cu,
                                                 float* __restrict__ ob) {
    const int bh = blockIdx.x;
    const int b = bh >> 4, h = bh & 15, hk = h >> 1;
    const int tid = threadIdx.x;
    const int lane = tid & 63, w = tid >> 6;
    __shared__ float kq[2][128];     // [buf][0:64 = k, 64:128 = q]
    __shared__ float pks[4][64];
    __shared__ float pqs[4][64];
    __shared__ float pqk[4];
    float S[16];
#pragma unroll
    for (int i = 0; i < 16; ++i) S[i] = 0.f;

    const int t0 = cu[b], t1 = cu[b + 1];

    // prefetch first token
    float pk = 0.f;
    if (tid < 128)
        pk = (tid < 64) ? kb[(size_t)t0 * KEY_DIM + hk * 64 + lane]
                        : qb[(size_t)t0 * KEY_DIM + hk * 64 + lane];
    float pg = gammab[t0 * HV + h];
    float pb = betab[t0 * HV + h];
    float pv = vb[(size_t)t0 * VAL_DIM + h * 64 + lane];

    int buf = 0;
    for (int tok = t0; tok < t1; ++tok) {
        if (tid < 128) kq[buf][tid] = pk;
        const float g = pg, bet = pb, vv = pv;
        __syncthreads();  // B1: kq[buf] staged; prev-step pks/pqs reads done

        // prefetch next token (overlaps compute below)
        const int nt = tok + 1;
        if (nt < t1) {
            if (tid < 128)
                pk = (tid < 64) ? kb[(size_t)nt * KEY_DIM + hk * 64 + lane]
                                : qb[(size_t)nt * KEY_DIM + hk * 64 + lane];
            pg = gammab[nt * HV + h];
            pb = betab[nt * HV + h];
            pv = vb[(size_t)nt * VAL_DIM + h * 64 + lane];
        }

        // cache this wave's 16 k and q values in registers
        float kr[16], qr[16];
#pragma unroll
        for (int i = 0; i < 16; ++i) {
            kr[i] = kq[buf][w * 16 + i];
            qr[i] = kq[buf][64 + w * 16 + i];
        }

        // one pass over γS: ks, qs partials (4 accumulators) + qk partial
        float a0 = 0.f, a1 = 0.f, a2 = 0.f, a3 = 0.f;
        float b0 = 0.f, b1 = 0.f, b2 = 0.f, b3 = 0.f;
        float c0 = 0.f, c1 = 0.f, c2 = 0.f, c3 = 0.f;
#pragma unroll
        for (int i = 0; i < 16; i += 4) {
            S[i + 0] *= g; a0 += kr[i + 0] * S[i + 0]; b0 += qr[i + 0] * S[i + 0]; c0 += qr[i + 0] * kr[i + 0];
            S[i + 1] *= g; a1 += kr[i + 1] * S[i + 1]; b1 += qr[i + 1] * S[i + 1]; c1 += qr[i + 1] * kr[i + 1];
            S[i + 2] *= g; a2 += kr[i + 2] * S[i + 2]; b2 += qr[i + 2] * S[i + 2]; c2 += qr[i + 2] * kr[i + 2];
            S[i + 3] *= g; a3 += kr[i + 3] * S[i + 3]; b3 += qr[i + 3] * S[i + 3]; c3 += qr[i + 3] * kr[i + 3];
        }
        pks[w][lane] = (a0 + a1) + (a2 + a3);
        pqs[w][lane] = (b0 + b1) + (b2 + b3);
        if (lane == 0) pqk[w] = (c0 + c1) + (c2 + c3);
        __syncthreads();  // B2: partials ready

        const float ks = (pks[0][lane] + pks[1][lane]) + (pks[2][lane] + pks[3][lane]);
        const float qs = (pqs[0][lane] + pqs[1][lane]) + (pqs[2][lane] + pqs[3][lane]);
        const float qk = (pqk[0] + pqk[1]) + (pqk[2] + pqk[3]);
        const float u = bet * (vv - ks);
#pragma unroll
        for (int i = 0; i < 16; ++i) S[i] += kr[i] * u;
        if (w == 0)
            ob[(size_t)tok * VAL_DIM + h * 64 + lane] = qs + qk * u;
        buf ^= 1;
    }
}

// ---------------------------------------------------------------------------
// Gated RMSNorm (in-place): o * rsqrt(mean(o^2)+eps) * nw * silu(z).
// ---------------------------------------------------------------------------
__global__ __launch_bounds__(256) void gated_norm(float* __restrict__ ob,
                                                  const float* __restrict__ zb,
                                                  const float* __restrict__ nw) {
    const int wid = blockIdx.x * 4 + (threadIdx.x >> 6);
    const int lane = threadIdx.x & 63;
    const int tok = wid >> 4, h = wid & 15;
    const size_t idx = (size_t)tok * VAL_DIM + h * 64 + lane;
    const float o = ob[idx];
    float ss = o * o;
#pragma unroll
    for (int m = 1; m < 64; m <<= 1) ss += __shfl_xor(ss, m);
    const float r = rsqrtf(ss * (1.f / 64.f) + 1e-6f);
    const float z = zb[idx];
    const float sz = z / (1.f + expf(-z));
    ob[idx] = o * r * nw[lane] * sz;
}

// ---------------------------------------------------------------------------
extern "C" void kernel_launch(void* const* d_in, const int* in_sizes, int n_in,
                              void* d_out, int out_size, void* d_ws, size_t ws_size,
                              hipStream_t stream) {
    const float* H    = (const float*)d_in[0];
    const float* Wqkv = (const float*)d_in[1];
    const float* Wz   = (const float*)d_in[2];
    const float* Wb   = (const float*)d_in[3];
    const float* Wa   = (const float*)d_in[4];
    const float* cwt  = (const float*)d_in[5];
    const float* dtb  = (const float*)d_in[6];
    const float* Alog = (const float*)d_in[7];
    const float* nw   = (const float*)d_in[8];
    const float* Wout = (const float*)d_in[9];
    const int*   cu   = (const int*)d_in[10];
    float* out = (float*)d_out;   // reference output dtype is FP32

    // --- Workspace (all fp32), ~25.4 MB (ws_size >= 44.8 MB inferred R1-R3) ---
    float* wsf = (float*)d_ws;
    float* mixed = wsf;                                  // 3,145,728 (gemm1->conv)
    float* obuf  = wsf;                                  // 1,572,864 alias of dead mixed
    float* qbuf  = wsf + (size_t)TOTAL * CONV_DIM;       //   786,432
    float* kbuf  = qbuf + (size_t)TOTAL * KEY_DIM;       //   786,432
    float* vbuf  = kbuf + (size_t)TOTAL * KEY_DIM;       // 1,572,864
    float* zbuf  = qbuf;                                 // alias of dead q+k
    float* gbuf  = vbuf + (size_t)TOTAL * VAL_DIM;       //    24,576
    float* bbuf  = gbuf + (size_t)TOTAL * HV;            //    24,576

    // 1) mixed = H @ W_qkv^T   (1536 x 2048)
    gemm_tn<<<dim3(CONV_DIM / 64, TOTAL / 64), 256, 0, stream>>>(
        H, Wqkv, mixed, TOTAL, CONV_DIM, HIDDEN);
    // 2) beta / gamma
    proj_ba<<<TOTAL, 64, 0, stream>>>(H, Wb, Wa, dtb, Alog, bbuf, gbuf);
    // 3) conv + silu + l2 norm -> q,k,v
    conv_norm<<<TOTAL, 256, 0, stream>>>(mixed, cwt, cu, qbuf, kbuf, vbuf);
    // 4) gated delta recurrence -> o (aliases dead mixed)
    delta_rec<<<NSEQ * HV, 256, 0, stream>>>(qbuf, kbuf, vbuf, gbuf, bbuf, cu, obuf);
    // 5) z = H @ W_z^T (aliases dead q+k)
    gemm_tn<<<dim3(VAL_DIM / 64, TOTAL / 64), 256, 0, stream>>>(
        H, Wz, zbuf, TOTAL, VAL_DIM, HIDDEN);
    // 6) gated RMSNorm in-place on o
    gated_norm<<<TOTAL * HV / 4, 256, 0, stream>>>(obuf, zbuf, nw);
    // 7) out = o @ W_out^T -> fp32 d_out
    gemm_tn<<<dim3(HIDDEN / 64, TOTAL / 64), 256, 0, stream>>>(
        obuf, Wout, out, TOTAL, HIDDEN, VAL_DIM);
}